// Round 3
// baseline (1183.031 us; speedup 1.0000x reference)
//
#include <hip/hip_runtime.h>
#include <math.h>

// CausalAttention: B=4, S=4096, DIN=DOUT=768, fp32 in/out, bf16 MFMA compute.
// ws layout: [0,256) unused | xb bf16 | q bf16 (pre-scaled) | k bf16 |
//            vT bf16 [b][d][s] | Wt bf16 (3x transposed W)

typedef unsigned short u16;
typedef unsigned int u32;
typedef __attribute__((ext_vector_type(8))) __bf16 bf8;
typedef __attribute__((ext_vector_type(4))) float f32x4;

struct __align__(8) U4 { u16 x, y, z, w; };

#define LOG2E 1.4426950408889634f
#define QSCALE 0.03608439182435161f   // 1/sqrt(768)

#define SBAR() __builtin_amdgcn_s_barrier()
#define WAIT_LGKM0() asm volatile("s_waitcnt lgkmcnt(0)" ::: "memory")
#define WAIT_VM8() asm volatile("s_waitcnt vmcnt(8)" ::: "memory")
#define WAIT_VM0() asm volatile("s_waitcnt vmcnt(0)" ::: "memory")

__device__ __forceinline__ u16 f2bf(float f) {
  u32 u = __builtin_bit_cast(u32, f);
  u += 0x7FFFu + ((u >> 16) & 1u);      // RNE
  return (u16)(u >> 16);
}
__device__ __forceinline__ f32x4 mfma16(bf8 a, bf8 b, f32x4 c) {
  return __builtin_amdgcn_mfma_f32_16x16x32_bf16(a, b, c, 0, 0, 0);
}
__device__ __forceinline__ void stage16(const void* g, void* l) {
  __builtin_amdgcn_global_load_lds((const __attribute__((address_space(1))) void*)g,
                                   (__attribute__((address_space(3))) void*)l, 16, 0, 0);
}
// XOR swizzle for gemm (128B rows): key bits >=7 -> bits 4-6
__device__ __forceinline__ u32 swz7(u32 off) { return off ^ (((off >> 7) & 7u) << 4); }

// ---------------- convert x (fp32 -> bf16), vectorized ----------------
__global__ void cvt_x_kernel(const float* __restrict__ x, u16* __restrict__ xb) {
  int i = blockIdx.x * 256 + threadIdx.x;          // float4 index, exact grid
  float4 v = ((const float4*)x)[i];
  U4 o; o.x = f2bf(v.x); o.y = f2bf(v.y); o.z = f2bf(v.z); o.w = f2bf(v.w);
  ((U4*)xb)[i] = o;
}

// ---------------- convert + transpose W: Wt[z][n][k] = bf16(W_z[k][n]) ----------------
__global__ void cvt_w_kernel(const float* __restrict__ Wq, const float* __restrict__ Wk,
                             const float* __restrict__ Wv, u16* __restrict__ wt) {
  __shared__ float tile[32][33];
  int z = blockIdx.z;
  const float* W = (z == 0) ? Wq : ((z == 1) ? Wk : Wv);
  u16* o = wt + (size_t)z * 589824;
  int n0 = blockIdx.x * 32, k0 = blockIdx.y * 32;
  int c = threadIdx.x & 31, r0 = threadIdx.x >> 5;
#pragma unroll
  for (int p = 0; p < 4; p++) tile[r0 + p * 8][c] = W[(size_t)(k0 + r0 + p * 8) * 768 + n0 + c];
  __syncthreads();
#pragma unroll
  for (int p = 0; p < 4; p++) o[(size_t)(n0 + r0 + p * 8) * 768 + k0 + c] = f2bf(tile[c][r0 + p * 8]);
}

// ---------------- QKV GEMM: C[16384x768] = xb * W_z, 128x128 tile, BK=64 ----------------
__global__ __launch_bounds__(256) void gemm_qkv_kernel(
    const u16* __restrict__ xb, const u16* __restrict__ wt,
    u16* __restrict__ qo, u16* __restrict__ ko, u16* __restrict__ vT) {
  __shared__ char lA[16384];
  __shared__ char lB[16384];
  const int tid = threadIdx.x;
  const int lane = tid & 63, wvid = tid >> 6;
  const int wm = wvid >> 1, wn = wvid & 1;
  const int l15 = lane & 15, lg4 = lane >> 4;
  const int m0 = blockIdx.x * 128;
  const int n0 = blockIdx.y * 128;
  const int z = blockIdx.z;
  const u16* wz = wt + (size_t)z * 589824;

  f32x4 acc[4][4];
#pragma unroll
  for (int rt = 0; rt < 4; rt++)
#pragma unroll
    for (int nt = 0; nt < 4; nt++) acc[rt][nt] = f32x4{0.f, 0.f, 0.f, 0.f};

  for (int kt = 0; kt < 12; kt++) {
#pragma unroll
    for (int i = 0; i < 4; i++) {
      u32 o = (u32)i * 4096u + (u32)wvid * 1024u + (u32)lane * 16u;
      u32 lg = swz7(o);
      u32 row = lg >> 7, kbyt = lg & 127u;
      stage16((const char*)xb + ((size_t)(m0 + row) * 1536 + (size_t)kt * 128 + kbyt),
              lA + (size_t)i * 4096 + (size_t)wvid * 1024);
      stage16((const char*)wz + ((size_t)(n0 + row) * 1536 + (size_t)kt * 128 + kbyt),
              lB + (size_t)i * 4096 + (size_t)wvid * 1024);
    }
    __syncthreads();
#pragma unroll
    for (int kk = 0; kk < 2; kk++) {
      bf8 af[4], bfr[4];
#pragma unroll
      for (int rt = 0; rt < 4; rt++) {
        u32 off = (u32)(wm * 64 + rt * 16 + l15) * 128u + (u32)kk * 64u + (u32)lg4 * 16u;
        af[rt] = *(const bf8*)(const void*)(lA + swz7(off));
      }
#pragma unroll
      for (int nt = 0; nt < 4; nt++) {
        u32 off = (u32)(wn * 64 + nt * 16 + l15) * 128u + (u32)kk * 64u + (u32)lg4 * 16u;
        bfr[nt] = *(const bf8*)(const void*)(lB + swz7(off));
      }
#pragma unroll
      for (int rt = 0; rt < 4; rt++)
#pragma unroll
        for (int nt = 0; nt < 4; nt++) acc[rt][nt] = mfma16(af[rt], bfr[nt], acc[rt][nt]);
    }
    __syncthreads();
  }
  if (z == 2) {
#pragma unroll
    for (int rt = 0; rt < 4; rt++) {
      int m = m0 + wm * 64 + rt * 16 + lg4 * 4;
      int batch = m >> 12;
      int s = m & 4095;
#pragma unroll
      for (int nt = 0; nt < 4; nt++) {
        int col = n0 + wn * 64 + nt * 16 + l15;
        U4 pk;
        pk.x = f2bf(acc[rt][nt][0]); pk.y = f2bf(acc[rt][nt][1]);
        pk.z = f2bf(acc[rt][nt][2]); pk.w = f2bf(acc[rt][nt][3]);
        *(U4*)(vT + ((size_t)batch * 768 + col) * 4096 + s) = pk;
      }
    }
  } else {
    u16* dst = (z == 0) ? qo : ko;
    float scl = (z == 0) ? QSCALE : 1.0f;
#pragma unroll
    for (int rt = 0; rt < 4; rt++)
#pragma unroll
      for (int nt = 0; nt < 4; nt++) {
        int col = n0 + wn * 64 + nt * 16 + l15;
#pragma unroll
        for (int j = 0; j < 4; j++) {
          int m = m0 + wm * 64 + rt * 16 + lg4 * 4 + j;
          dst[(size_t)m * 768 + col] = f2bf(acc[rt][nt][j] * scl);
        }
      }
  }
}

// ---------------- flash attention v3: 8 waves, BQ=64, KBLK=128 ----------------
// QK^T: rg=wv>>1 (16 q-rows), cg=wv&1 (64 keys). K staged in LDS, 3 D-chunks of
// 256, double-buffered, pipelined 1 chunk ahead with counted vmcnt + raw barriers.
// PV: wave wv owns output cols [wv*96, +96). V direct from global (vT layout).
// K chunk LDS [128 keys][512B], XOR swizzle bits4-6 ^= key&7. P [64][256B], same.
__global__ __launch_bounds__(512, 2) void attn_kernel(
    const u16* __restrict__ qg, const u16* __restrict__ kg, const u16* __restrict__ vg,
    float* __restrict__ out) {
  __shared__ char Klds[2][65536];
  __shared__ char Plds[16384];
  __shared__ float pm[4][2][16];
  __shared__ float ps[4][2][16];
  __shared__ float mrun[64], lrun[64], alpha_s[64];

  const int tid = threadIdx.x;
  const int lane = tid & 63;
  const int wv = tid >> 6;           // 0..7
  const int rg = wv >> 1;            // 0..3
  const int cg = wv & 1;             // 0..1
  const int l15 = lane & 15, lg4 = lane >> 4;

  const int b = blockIdx.x;
  const int qb_i = 63 - (b >> 2);    // biggest tasks first
  const int batch = b & 3;
  const int qbase = qb_i * 64;
  const size_t boff = (size_t)batch * 4096;
  const int ntile = (qb_i >> 1) + 1;
  const int gtot = ntile * 3;

  if (tid < 64) { mrun[tid] = -INFINITY; lrun[tid] = 0.f; }

  // per-thread staging source offsets (element units within a chunk)
  u32 soff[8];
#pragma unroll
  for (int p = 0; p < 8; p++) {
    u32 o = (u32)p * 8192u + (u32)wv * 1024u + (u32)lane * 16u;
    u32 lo = o ^ (((o >> 9) & 7u) << 4);
    soff[p] = (lo >> 9) * 768u + ((lo & 511u) >> 1);
  }

  // Q fragments in registers: row = qbase + rg*16 + l15, 24 k-slices
  bf8 qf[24];
  {
    const u16* qrow = qg + (boff + qbase + rg * 16 + l15) * 768 + lg4 * 8;
#pragma unroll
    for (int t = 0; t < 24; t++) qf[t] = *(const bf8*)(const void*)(qrow + t * 32);
  }

  f32x4 acc[4][6];
#pragma unroll
  for (int rt = 0; rt < 4; rt++)
#pragma unroll
    for (int ct = 0; ct < 6; ct++) acc[rt][ct] = f32x4{0.f, 0.f, 0.f, 0.f};

  const u16* kbase = kg + boff * 768;
  // prologue: stage chunk g=0 into buf0
  {
#pragma unroll
    for (int p = 0; p < 8; p++)
      stage16(kbase + soff[p], Klds[0] + p * 8192 + wv * 1024);
  }

  const u32 kmask = (u32)(l15 & 7) << 4;

  for (int kt = 0; kt < ntile; kt++) {
    const int kb = kt * 128;
    f32x4 sv[4];
#pragma unroll
    for (int ct = 0; ct < 4; ct++) sv[ct] = f32x4{0.f, 0.f, 0.f, 0.f};

#pragma unroll
    for (int c = 0; c < 3; c++) {
      const int g = kt * 3 + c;
      if (g + 1 < gtot) {
        const int g1 = g + 1;
        const int kt1 = g1 / 3;
        const int c1 = g1 - kt1 * 3;
        const u16* src = kbase + (size_t)(kt1 * 128) * 768 + c1 * 256;
        char* dstb = Klds[g1 & 1];
#pragma unroll
        for (int p = 0; p < 8; p++)
          stage16(src + soff[p], dstb + p * 8192 + wv * 1024);
        WAIT_VM8();
      } else {
        WAIT_VM0();
      }
      SBAR();                                    // chunk g staged, buf free
      const char* kbuf = Klds[g & 1];
#pragma unroll
      for (int ks = 0; ks < 8; ks++) {
#pragma unroll
        for (int ct = 0; ct < 4; ct++) {
          u32 key = (u32)(cg * 64 + ct * 16 + l15);
          u32 addr = (key * 512u + (u32)ks * 64u + (u32)lg4 * 16u) ^ kmask;
          bf8 kf = *(const bf8*)(const void*)(kbuf + addr);
          sv[ct] = mfma16(qf[c * 8 + ks], kf, sv[ct]);
        }
      }
      SBAR();                                    // all reads of buf g&1 done
    }

    // causal mask (only last tile crosses the diagonal)
    if (kt == ntile - 1) {
      const int rowg = qbase + rg * 16 + lg4 * 4;
#pragma unroll
      for (int ct = 0; ct < 4; ct++) {
        int col = kb + cg * 64 + ct * 16 + l15;
#pragma unroll
        for (int j = 0; j < 4; j++) if (col > rowg + j) sv[ct][j] = -INFINITY;
      }
    }
    // per-row max over this wave's 64 keys
    float rmax[4];
#pragma unroll
    for (int j = 0; j < 4; j++) {
      float m = fmaxf(fmaxf(sv[0][j], sv[1][j]), fmaxf(sv[2][j], sv[3][j]));
      m = fmaxf(m, __shfl_xor(m, 1));
      m = fmaxf(m, __shfl_xor(m, 2));
      m = fmaxf(m, __shfl_xor(m, 4));
      m = fmaxf(m, __shfl_xor(m, 8));
      rmax[j] = m;
    }
    if (l15 == 0) {
#pragma unroll
      for (int j = 0; j < 4; j++) pm[rg][cg][lg4 * 4 + j] = rmax[j];
    }
    WAIT_LGKM0(); SBAR();                        // b1
    if (tid < 64) {
      float mo = mrun[tid];
      float mn = fmaxf(mo, fmaxf(pm[tid >> 4][0][tid & 15], pm[tid >> 4][1][tid & 15]));
      alpha_s[tid] = exp2f((mo - mn) * LOG2E);
      mrun[tid] = mn;
    }
    WAIT_LGKM0(); SBAR();                        // b2
    // p = exp(s-m), write P (bf16, swizzled), partial row sums
    {
      const int row0 = rg * 16 + lg4 * 4;
      float psum[4];
#pragma unroll
      for (int j = 0; j < 4; j++) {
        const int row = row0 + j;
        const float mrow = mrun[row];
        const u32 wmask = (u32)(row & 7) << 4;
        float su = 0.f;
#pragma unroll
        for (int ct = 0; ct < 4; ct++) {
          float p = exp2f((sv[ct][j] - mrow) * LOG2E);
          su += p;
          u32 off = ((u32)row * 256u + (u32)(cg * 64 + ct * 16 + l15) * 2u) ^ wmask;
          *(u16*)(void*)(Plds + off) = f2bf(p);
        }
        su += __shfl_xor(su, 1);
        su += __shfl_xor(su, 2);
        su += __shfl_xor(su, 4);
        su += __shfl_xor(su, 8);
        psum[j] = su;
      }
      if (l15 == 0) {
#pragma unroll
        for (int j = 0; j < 4; j++) ps[rg][cg][lg4 * 4 + j] = psum[j];
      }
    }
    // rescale O accumulators (rows span all 64)
    {
      float al[16];
#pragma unroll
      for (int rt = 0; rt < 4; rt++)
#pragma unroll
        for (int j = 0; j < 4; j++) al[rt * 4 + j] = alpha_s[rt * 16 + lg4 * 4 + j];
#pragma unroll
      for (int rt = 0; rt < 4; rt++)
#pragma unroll
        for (int ct = 0; ct < 6; ct++)
#pragma unroll
          for (int j = 0; j < 4; j++) acc[rt][ct][j] *= al[rt * 4 + j];
    }
    WAIT_LGKM0(); SBAR();                        // b3: P + ps visible
    if (tid < 64)
      lrun[tid] = lrun[tid] * alpha_s[tid] + ps[tid >> 4][0][tid & 15] + ps[tid >> 4][1][tid & 15];
    // ---- PV: O[64 x 96] += P[64x128] * V[128x96] per wave, V direct ----
    const u16* vb0 = vg + ((size_t)batch * 768 + wv * 96 + l15) * 4096 + kb + lg4 * 8;
#pragma unroll
    for (int ks = 0; ks < 4; ks++) {
      bf8 pa[4];
#pragma unroll
      for (int rt = 0; rt < 4; rt++) {
        u32 addr = ((u32)(rt * 16 + l15) * 256u + (u32)ks * 64u + (u32)lg4 * 16u) ^ kmask;
        pa[rt] = *(const bf8*)(const void*)(Plds + addr);
      }
#pragma unroll
      for (int ct = 0; ct < 6; ct++) {
        bf8 vb = *(const bf8*)(const void*)(vb0 + (size_t)(ct * 16) * 4096 + ks * 32);
#pragma unroll
        for (int rt = 0; rt < 4; rt++)
          acc[rt][ct] = mfma16(pa[rt], vb, acc[rt][ct]);
      }
    }
  }
  WAIT_LGKM0(); SBAR();                          // lrun final visible
  // ---- epilogue: normalize and store fp32 ----
  float inv[16];
#pragma unroll
  for (int rt = 0; rt < 4; rt++)
#pragma unroll
    for (int j = 0; j < 4; j++) inv[rt * 4 + j] = 1.f / lrun[rt * 16 + lg4 * 4 + j];
#pragma unroll
  for (int rt = 0; rt < 4; rt++)
#pragma unroll
    for (int ct = 0; ct < 6; ct++)
#pragma unroll
      for (int j = 0; j < 4; j++) {
        size_t o = (boff + (size_t)(qbase + rt * 16 + lg4 * 4 + j)) * 768 + wv * 96 + ct * 16 + l15;
        out[o] = acc[rt][ct][j] * inv[rt * 4 + j];
      }
}

extern "C" void kernel_launch(void* const* d_in, const int* in_sizes, int n_in,
                              void* d_out, int out_size, void* d_ws, size_t ws_size,
                              hipStream_t stream) {
  const float* x  = (const float*)d_in[0];
  const float* Wq = (const float*)d_in[1];
  const float* Wk = (const float*)d_in[2];
  const float* Wv = (const float*)d_in[3];
  float* out = (float*)d_out;

  char* ws = (char*)d_ws;
  u16* xb = (u16*)(ws + 256);
  u16* qb = xb + 12582912;
  u16* kb = qb + 12582912;
  u16* vT = kb + 12582912;
  u16* wt = vT + 12582912;     // 3 x 589824

  cvt_x_kernel<<<12288, 256, 0, stream>>>(x, xb);
  cvt_w_kernel<<<dim3(24, 24, 3), 256, 0, stream>>>(Wq, Wk, Wv, wt);
  gemm_qkv_kernel<<<dim3(128, 6, 3), 256, 0, stream>>>(xb, wt, qb, kb, vT);
  attn_kernel<<<256, 512, 0, stream>>>(qb, kb, vT, out);
}

// Round 4
// 550.104 us; speedup vs baseline: 2.1506x; 2.1506x over previous
//
#include <hip/hip_runtime.h>
#include <math.h>

// CausalAttention: B=4, S=4096, DIN=DOUT=768, fp32 in/out, bf16 MFMA compute.
// ws layout: [0,256) unused | xb bf16 | q bf16 (pre-scaled) | k bf16 |
//            vT bf16 [b][d][s] | Wt bf16 (3x transposed W)

typedef unsigned short u16;
typedef unsigned int u32;
typedef __attribute__((ext_vector_type(8))) __bf16 bf8;
typedef __attribute__((ext_vector_type(4))) float f32x4;

struct __align__(8) U4 { u16 x, y, z, w; };

#define LOG2E 1.4426950408889634f
#define QSCALE 0.03608439182435161f   // 1/sqrt(768)

#define SBAR() __builtin_amdgcn_s_barrier()
#define WAIT_LGKM0() asm volatile("s_waitcnt lgkmcnt(0)" ::: "memory")
#define WAIT_VM4() asm volatile("s_waitcnt vmcnt(4)" ::: "memory")
#define WAIT_VM0() asm volatile("s_waitcnt vmcnt(0)" ::: "memory")

__device__ __forceinline__ u16 f2bf(float f) {
  u32 u = __builtin_bit_cast(u32, f);
  u += 0x7FFFu + ((u >> 16) & 1u);      // RNE
  return (u16)(u >> 16);
}
__device__ __forceinline__ f32x4 mfma16(bf8 a, bf8 b, f32x4 c) {
  return __builtin_amdgcn_mfma_f32_16x16x32_bf16(a, b, c, 0, 0, 0);
}
__device__ __forceinline__ void stage16(const void* g, void* l) {
  __builtin_amdgcn_global_load_lds((const __attribute__((address_space(1))) void*)g,
                                   (__attribute__((address_space(3))) void*)l, 16, 0, 0);
}
// XOR swizzle for gemm (128B rows): key bits >=7 -> bits 4-6
__device__ __forceinline__ u32 swz7(u32 off) { return off ^ (((off >> 7) & 7u) << 4); }

// ---------------- convert x (fp32 -> bf16), vectorized ----------------
__global__ void cvt_x_kernel(const float* __restrict__ x, u16* __restrict__ xb) {
  int i = blockIdx.x * 256 + threadIdx.x;          // float4 index, exact grid
  float4 v = ((const float4*)x)[i];
  U4 o; o.x = f2bf(v.x); o.y = f2bf(v.y); o.z = f2bf(v.z); o.w = f2bf(v.w);
  ((U4*)xb)[i] = o;
}

// ---------------- convert + transpose W: Wt[z][n][k] = bf16(W_z[k][n]) ----------------
__global__ void cvt_w_kernel(const float* __restrict__ Wq, const float* __restrict__ Wk,
                             const float* __restrict__ Wv, u16* __restrict__ wt) {
  __shared__ float tile[32][33];
  int z = blockIdx.z;
  const float* W = (z == 0) ? Wq : ((z == 1) ? Wk : Wv);
  u16* o = wt + (size_t)z * 589824;
  int n0 = blockIdx.x * 32, k0 = blockIdx.y * 32;
  int c = threadIdx.x & 31, r0 = threadIdx.x >> 5;
#pragma unroll
  for (int p = 0; p < 4; p++) tile[r0 + p * 8][c] = W[(size_t)(k0 + r0 + p * 8) * 768 + n0 + c];
  __syncthreads();
#pragma unroll
  for (int p = 0; p < 4; p++) o[(size_t)(n0 + r0 + p * 8) * 768 + k0 + c] = f2bf(tile[c][r0 + p * 8]);
}

// ---------------- QKV GEMM: C[16384x768] = xb * W_z, 128x128 tile, BK=64 ----------------
__global__ __launch_bounds__(256) void gemm_qkv_kernel(
    const u16* __restrict__ xb, const u16* __restrict__ wt,
    u16* __restrict__ qo, u16* __restrict__ ko, u16* __restrict__ vT) {
  __shared__ char lA[16384];
  __shared__ char lB[16384];
  const int tid = threadIdx.x;
  const int lane = tid & 63, wvid = tid >> 6;
  const int wm = wvid >> 1, wn = wvid & 1;
  const int l15 = lane & 15, lg4 = lane >> 4;
  const int m0 = blockIdx.x * 128;
  const int n0 = blockIdx.y * 128;
  const int z = blockIdx.z;
  const u16* wz = wt + (size_t)z * 589824;

  f32x4 acc[4][4];
#pragma unroll
  for (int rt = 0; rt < 4; rt++)
#pragma unroll
    for (int nt = 0; nt < 4; nt++) acc[rt][nt] = f32x4{0.f, 0.f, 0.f, 0.f};

  for (int kt = 0; kt < 12; kt++) {
#pragma unroll
    for (int i = 0; i < 4; i++) {
      u32 o = (u32)i * 4096u + (u32)wvid * 1024u + (u32)lane * 16u;
      u32 lg = swz7(o);
      u32 row = lg >> 7, kbyt = lg & 127u;
      stage16((const char*)xb + ((size_t)(m0 + row) * 1536 + (size_t)kt * 128 + kbyt),
              lA + (size_t)i * 4096 + (size_t)wvid * 1024);
      stage16((const char*)wz + ((size_t)(n0 + row) * 1536 + (size_t)kt * 128 + kbyt),
              lB + (size_t)i * 4096 + (size_t)wvid * 1024);
    }
    __syncthreads();
#pragma unroll
    for (int kk = 0; kk < 2; kk++) {
      bf8 af[4], bfr[4];
#pragma unroll
      for (int rt = 0; rt < 4; rt++) {
        u32 off = (u32)(wm * 64 + rt * 16 + l15) * 128u + (u32)kk * 64u + (u32)lg4 * 16u;
        af[rt] = *(const bf8*)(const void*)(lA + swz7(off));
      }
#pragma unroll
      for (int nt = 0; nt < 4; nt++) {
        u32 off = (u32)(wn * 64 + nt * 16 + l15) * 128u + (u32)kk * 64u + (u32)lg4 * 16u;
        bfr[nt] = *(const bf8*)(const void*)(lB + swz7(off));
      }
#pragma unroll
      for (int rt = 0; rt < 4; rt++)
#pragma unroll
        for (int nt = 0; nt < 4; nt++) acc[rt][nt] = mfma16(af[rt], bfr[nt], acc[rt][nt]);
    }
    __syncthreads();
  }
  if (z == 2) {
#pragma unroll
    for (int rt = 0; rt < 4; rt++) {
      int m = m0 + wm * 64 + rt * 16 + lg4 * 4;
      int batch = m >> 12;
      int s = m & 4095;
#pragma unroll
      for (int nt = 0; nt < 4; nt++) {
        int col = n0 + wn * 64 + nt * 16 + l15;
        U4 pk;
        pk.x = f2bf(acc[rt][nt][0]); pk.y = f2bf(acc[rt][nt][1]);
        pk.z = f2bf(acc[rt][nt][2]); pk.w = f2bf(acc[rt][nt][3]);
        *(U4*)(vT + ((size_t)batch * 768 + col) * 4096 + s) = pk;
      }
    }
  } else {
    u16* dst = (z == 0) ? qo : ko;
    float scl = (z == 0) ? QSCALE : 1.0f;
#pragma unroll
    for (int rt = 0; rt < 4; rt++)
#pragma unroll
      for (int nt = 0; nt < 4; nt++) {
        int col = n0 + wn * 64 + nt * 16 + l15;
#pragma unroll
        for (int j = 0; j < 4; j++) {
          int m = m0 + wm * 64 + rt * 16 + lg4 * 4 + j;
          dst[(size_t)m * 768 + col] = f2bf(acc[rt][nt][j] * scl);
        }
      }
  }
}

// ---------------- flash attention v4: 8 waves, BQ=32, KBLK=128 ----------------
// K streamed via global_load_lds DMA: 6 chunks/tile of [128 keys][128 d] = 32 KB,
// 3 rotating buffers, issued 2 ahead, counted vmcnt(4), raw s_barrier (no drains).
// QK^T: rg=wv>>2 (16 rows), cg=wv&3 (32 keys). PV: wave owns cols [wv*96,+96),
// V direct from global (vT [b][d][s]) with register double-buffer over ks.
// Q in LDS subtiled [24 tt][32 rows][64B], slot-permuted. P [32][256B] XOR-swz.
__global__ __attribute__((amdgpu_flat_work_group_size(512, 512)))
__attribute__((amdgpu_waves_per_eu(2, 2))) void attn_kernel(
    const u16* __restrict__ qg, const u16* __restrict__ kg, const u16* __restrict__ vg,
    float* __restrict__ out) {
  __shared__ char Qlds[49152];
  __shared__ char Klds[3][32768];
  __shared__ char Plds[8192];
  __shared__ float pm[2][4][16];
  __shared__ float ps[2][4][16];
  __shared__ float mrun[32], lrun[32], alpha_s[32];

  const int tid = threadIdx.x;
  const int lane = tid & 63;
  const int wv = tid >> 6;           // 0..7
  const int rg = wv >> 2;            // 0..1
  const int cg = wv & 3;             // 0..3
  const int l15 = lane & 15, lg4 = lane >> 4;

  // task map with XCD affinity: XCD = blockIdx%8 (round-robin); batch per XCD pair
  const int b = blockIdx.x;
  const int batch = (b >> 1) & 3;
  const int qb_i = 127 - (((b >> 3) << 1) + (b & 1));   // biggest first
  const int qbase = qb_i * 32;
  const size_t boff = (size_t)batch * 4096;
  const int ntile = (qb_i >> 2) + 1;
  const int gtot = ntile * 6;

  const u16* kbase = kg + boff * 768;

  // per-thread DMA source offsets (within a chunk): dest linear o, source swizzled
  u32 soff[4];
#pragma unroll
  for (int p = 0; p < 4; p++) {
    u32 o = (u32)p * 8192u + (u32)tid * 16u;
    u32 key = o >> 8;
    u32 dbyte = (o & 255u) ^ ((key & 7u) << 4);
    soff[p] = key * 768u + (dbyte >> 1);
  }

  // prologue: issue chunks 0 (d 0..127) and 1 (d 128..255); gtot >= 6 always
#pragma unroll
  for (int p = 0; p < 4; p++)
    stage16(kbase + soff[p], &Klds[0][p * 8192 + tid * 16]);
#pragma unroll
  for (int p = 0; p < 4; p++)
    stage16(kbase + soff[p] + 128u, &Klds[1][p * 8192 + tid * 16]);

  // ---- stage Q tile (32 x 768 bf16) into subtiled LDS ----
#pragma unroll
  for (int j = 0; j < 6; j++) {
    int li = j * 512 + tid;                    // 16B-chunk id, 0..3071
    int row = li / 96;
    int c16 = li - row * 96;                   // 0..95
    int tt = c16 >> 2, sl = c16 & 3;
    u32 daddr = (u32)tt * 2048u + (u32)row * 64u + (u32)((sl ^ ((row >> 1) & 3)) << 4);
    bf8 v = *(const bf8*)(const void*)(qg + (boff + qbase + row) * 768 + c16 * 8);
    *(bf8*)(void*)(Qlds + daddr) = v;
  }
  if (tid < 32) { mrun[tid] = -INFINITY; lrun[tid] = 0.f; }
  WAIT_LGKM0(); SBAR();

  // per-lane constants
  const int qrow_loc = rg * 16 + l15;
  const u32 qlds_base = (u32)qrow_loc * 64u + (u32)((lg4 ^ ((qrow_loc >> 1) & 3)) << 4);
  const u32 kxm = (u32)(l15 & 7) << 4;
  const u32 pa_col = ((u32)lg4 * 16u) ^ ((u32)(l15 & 3) << 4);   // P-read bits 4-5
  const u32 pa_kx = (u32)((l15 >> 2) & 1);                       // P-read bit 6

  f32x4 acc[2][6];
#pragma unroll
  for (int rt = 0; rt < 2; rt++)
#pragma unroll
    for (int ct = 0; ct < 6; ct++) acc[rt][ct] = f32x4{0.f, 0.f, 0.f, 0.f};

  for (int kt = 0; kt < ntile; kt++) {
    const int kb = kt * 128;
    f32x4 sv0 = f32x4{0.f, 0.f, 0.f, 0.f}, sv1 = sv0;

#pragma unroll
    for (int c = 0; c < 6; c++) {
      const int g = kt * 6 + c;
      if (g + 1 < gtot) { WAIT_VM4(); } else { WAIT_VM0(); }
      SBAR();                                  // chunk g staged; buffer c%3
      {
        const char* kbuf = Klds[c % 3];
#pragma unroll
        for (int ks = 0; ks < 4; ks++) {
          bf8 qv = *(const bf8*)(const void*)(Qlds + qlds_base + (u32)(c * 4 + ks) * 2048u);
          u32 inr = ((u32)ks * 64u + (u32)lg4 * 16u) ^ kxm;
          bf8 kv0 = *(const bf8*)(const void*)(kbuf + (u32)(cg * 32 + l15) * 256u + inr);
          bf8 kv1 = *(const bf8*)(const void*)(kbuf + (u32)(cg * 32 + 16 + l15) * 256u + inr);
          sv0 = mfma16(qv, kv0, sv0);
          sv1 = mfma16(qv, kv1, sv1);
        }
      }
      WAIT_LGKM0(); SBAR();                    // all reads of buffer c%3 done
      if (g + 2 < gtot) {                      // issue chunk g+2 into (c+2)%3
        const int g2 = g + 2;
        const int kt1 = g2 / 6, c1 = g2 - kt1 * 6;
        const u16* src = kbase + (size_t)(kt1 * 128) * 768 + c1 * 128;
        char* dstb = &Klds[(c + 2) % 3][0];
#pragma unroll
        for (int p = 0; p < 4; p++)
          stage16(src + soff[p], dstb + p * 8192 + tid * 16);
      }
    }

    // causal mask (only last tile crosses the diagonal)
    if (kt == ntile - 1) {
      const int rowg = qbase + rg * 16 + lg4 * 4;
      const int col0 = kb + cg * 32 + l15;
#pragma unroll
      for (int j = 0; j < 4; j++) {
        if (col0 > rowg + j) sv0[j] = -INFINITY;
        if (col0 + 16 > rowg + j) sv1[j] = -INFINITY;
      }
    }
    // per-row max over this wave's 32 keys
    float rmax[4];
#pragma unroll
    for (int j = 0; j < 4; j++) {
      float m = fmaxf(sv0[j], sv1[j]);
      m = fmaxf(m, __shfl_xor(m, 1));
      m = fmaxf(m, __shfl_xor(m, 2));
      m = fmaxf(m, __shfl_xor(m, 4));
      m = fmaxf(m, __shfl_xor(m, 8));
      rmax[j] = m;
    }
    if (l15 == 0) {
#pragma unroll
      for (int j = 0; j < 4; j++) pm[rg][cg][lg4 * 4 + j] = rmax[j];
    }
    WAIT_LGKM0(); SBAR();                      // b1
    if (tid < 32) {
      int r2 = tid >> 4, ix = tid & 15;
      float mo = mrun[tid];
      float mn = fmaxf(fmaxf(pm[r2][0][ix], pm[r2][1][ix]), fmaxf(pm[r2][2][ix], pm[r2][3][ix]));
      mn = fmaxf(mo, mn);
      alpha_s[tid] = exp2f((mo - mn) * LOG2E);
      mrun[tid] = mn;
    }
    WAIT_LGKM0(); SBAR();                      // b2
    // p = exp(s-m), write P (bf16, swizzled), partial row sums
    {
      float psum[4];
      const int prow0 = rg * 16 + lg4 * 4;
#pragma unroll
      for (int j = 0; j < 4; j++) {
        int r = prow0 + j;
        float mrow = mrun[r];
        float p0 = exp2f((sv0[j] - mrow) * LOG2E);
        float p1 = exp2f((sv1[j] - mrow) * LOG2E);
        u32 rb = (u32)r * 256u;
        u32 msk = (u32)(r & 7) << 4;
        *(u16*)(void*)(Plds + rb + (((u32)(cg * 32 + l15) * 2u) ^ msk)) = f2bf(p0);
        *(u16*)(void*)(Plds + rb + (((u32)(cg * 32 + 16 + l15) * 2u) ^ msk)) = f2bf(p1);
        float su = p0 + p1;
        su += __shfl_xor(su, 1);
        su += __shfl_xor(su, 2);
        su += __shfl_xor(su, 4);
        su += __shfl_xor(su, 8);
        psum[j] = su;
      }
      if (l15 == 0) {
#pragma unroll
        for (int j = 0; j < 4; j++) ps[rg][cg][lg4 * 4 + j] = psum[j];
      }
    }
    // rescale O accumulators + pre-issue V (ks=0)
    const u16* vb0 = vg + ((size_t)batch * 768 + wv * 96 + l15) * 4096 + kb + lg4 * 8;
    bf8 vcur0, vcur1, vcur2, vcur3, vcur4, vcur5;
    vcur0 = *(const bf8*)(const void*)(vb0);
    vcur1 = *(const bf8*)(const void*)(vb0 + 65536);
    vcur2 = *(const bf8*)(const void*)(vb0 + 131072);
    vcur3 = *(const bf8*)(const void*)(vb0 + 196608);
    vcur4 = *(const bf8*)(const void*)(vb0 + 262144);
    vcur5 = *(const bf8*)(const void*)(vb0 + 327680);
    {
      float al[8];
#pragma unroll
      for (int rt = 0; rt < 2; rt++)
#pragma unroll
        for (int j = 0; j < 4; j++) al[rt * 4 + j] = alpha_s[rt * 16 + lg4 * 4 + j];
#pragma unroll
      for (int ct = 0; ct < 6; ct++)
#pragma unroll
        for (int rt = 0; rt < 2; rt++)
#pragma unroll
          for (int j = 0; j < 4; j++) acc[rt][ct][j] *= al[rt * 4 + j];
    }
    WAIT_LGKM0(); SBAR();                      // b3: P + ps visible
    if (tid < 32) {
      int r2 = tid >> 4, ix = tid & 15;
      lrun[tid] = lrun[tid] * alpha_s[tid] +
                  ps[r2][0][ix] + ps[r2][1][ix] + ps[r2][2][ix] + ps[r2][3][ix];
    }
    // ---- PV: O[32 x 96] += P[32x128] * V[128x96], V reg-double-buffered ----
#pragma unroll
    for (int ks = 0; ks < 4; ks++) {
      u32 kss = ((u32)ks ^ pa_kx) * 64u;
      bf8 pa0 = *(const bf8*)(const void*)(Plds + (u32)l15 * 256u + pa_col + kss);
      bf8 pa1 = *(const bf8*)(const void*)(Plds + ((u32)l15 * 256u + 4096u) + pa_col + kss);
      bf8 vn0, vn1, vn2, vn3, vn4, vn5;
      if (ks < 3) {
        const u16* vnp = vb0 + (ks + 1) * 32;
        vn0 = *(const bf8*)(const void*)(vnp);
        vn1 = *(const bf8*)(const void*)(vnp + 65536);
        vn2 = *(const bf8*)(const void*)(vnp + 131072);
        vn3 = *(const bf8*)(const void*)(vnp + 196608);
        vn4 = *(const bf8*)(const void*)(vnp + 262144);
        vn5 = *(const bf8*)(const void*)(vnp + 327680);
      }
      acc[0][0] = mfma16(pa0, vcur0, acc[0][0]);  acc[1][0] = mfma16(pa1, vcur0, acc[1][0]);
      acc[0][1] = mfma16(pa0, vcur1, acc[0][1]);  acc[1][1] = mfma16(pa1, vcur1, acc[1][1]);
      acc[0][2] = mfma16(pa0, vcur2, acc[0][2]);  acc[1][2] = mfma16(pa1, vcur2, acc[1][2]);
      acc[0][3] = mfma16(pa0, vcur3, acc[0][3]);  acc[1][3] = mfma16(pa1, vcur3, acc[1][3]);
      acc[0][4] = mfma16(pa0, vcur4, acc[0][4]);  acc[1][4] = mfma16(pa1, vcur4, acc[1][4]);
      acc[0][5] = mfma16(pa0, vcur5, acc[0][5]);  acc[1][5] = mfma16(pa1, vcur5, acc[1][5]);
      if (ks < 3) {
        vcur0 = vn0; vcur1 = vn1; vcur2 = vn2; vcur3 = vn3; vcur4 = vn4; vcur5 = vn5;
      }
    }
  }
  WAIT_LGKM0(); SBAR();                        // lrun final visible
  // ---- epilogue: normalize and store fp32 ----
  float inv[8];
#pragma unroll
  for (int rt = 0; rt < 2; rt++)
#pragma unroll
    for (int j = 0; j < 4; j++) inv[rt * 4 + j] = 1.f / lrun[rt * 16 + lg4 * 4 + j];
#pragma unroll
  for (int ct = 0; ct < 6; ct++)
#pragma unroll
    for (int rt = 0; rt < 2; rt++)
#pragma unroll
      for (int j = 0; j < 4; j++) {
        size_t o = (boff + (size_t)(qbase + rt * 16 + lg4 * 4 + j)) * 768 + wv * 96 + ct * 16 + l15;
        out[o] = acc[rt][ct][j] * inv[rt * 4 + j];
      }
}

extern "C" void kernel_launch(void* const* d_in, const int* in_sizes, int n_in,
                              void* d_out, int out_size, void* d_ws, size_t ws_size,
                              hipStream_t stream) {
  const float* x  = (const float*)d_in[0];
  const float* Wq = (const float*)d_in[1];
  const float* Wk = (const float*)d_in[2];
  const float* Wv = (const float*)d_in[3];
  float* out = (float*)d_out;

  char* ws = (char*)d_ws;
  u16* xb = (u16*)(ws + 256);
  u16* qb = xb + 12582912;
  u16* kb = qb + 12582912;
  u16* vT = kb + 12582912;
  u16* wt = vT + 12582912;     // 3 x 589824

  cvt_x_kernel<<<12288, 256, 0, stream>>>(x, xb);
  cvt_w_kernel<<<dim3(24, 24, 3), 256, 0, stream>>>(Wq, Wk, Wv, wt);
  gemm_qkv_kernel<<<dim3(128, 6, 3), 256, 0, stream>>>(xb, wt, qb, kb, vT);
  attn_kernel<<<512, 512, 0, stream>>>(qb, kb, vT, out);
}